// Round 19
// baseline (399.386 us; speedup 1.0000x reference)
//
#include <hip/hip_runtime.h>
#include <math.h>

#define N_NODES 50000
#define N_EDGES 800000
#define HEADS 4
#define OUT_C 64
#define HC 256            // HEADS*OUT_C
#define NEG_SLOPE 0.2f
#define NBUCKET 196       // ceil(N_NODES/256)
#define CHUNK 1000
#define NBLK 800          // NBLK*CHUNK == N_EDGES exactly
#define WT_BLOCKS 64
#define GEMM_BLOCKS 3125  // N_NODES/16 row-groups
#define GEMM_WORKERS 256  // strip-mined: each worker block does ceil(3125/256) groups
#define LOG2E 1.44269504f

typedef __attribute__((ext_vector_type(8))) short bf16x8;
typedef __attribute__((ext_vector_type(4))) float f32x4;

// float -> bf16 (round-to-nearest-even); inputs are finite
__device__ inline unsigned short f2bf(float f) {
    unsigned u = __float_as_uint(f);
    return (unsigned short)((u + 0x7FFFu + ((u >> 16) & 1u)) >> 16);
}

// byte k of u32 -> float; LLVM pattern-matches to v_cvt_f32_ubyte{0..3}
__device__ inline float ub0(unsigned q) { return (float)(q & 0xFFu); }
__device__ inline float ub1(unsigned q) { return (float)((q >> 8) & 0xFFu); }
__device__ inline float ub2(unsigned q) { return (float)((q >> 16) & 0xFFu); }
__device__ inline float ub3(unsigned q) { return (float)(q >> 24); }

// sum across the 16 lanes of a DPP row (head group) via row_ror adds: pure VALU
__device__ inline float rowsum16(float p) {
    int y;
    y = __builtin_amdgcn_update_dpp(0, __float_as_int(p), 0x121, 0xF, 0xF, false);
    p += __int_as_float(y);
    y = __builtin_amdgcn_update_dpp(0, __float_as_int(p), 0x122, 0xF, 0xF, false);
    p += __int_as_float(y);
    y = __builtin_amdgcn_update_dpp(0, __float_as_int(p), 0x124, 0xF, 0xF, false);
    p += __int_as_float(y);
    y = __builtin_amdgcn_update_dpp(0, __float_as_int(p), 0x128, 0xF, 0xF, false);
    p += __int_as_float(y);
    return p;
}

__device__ inline void spin_until(int* flag, int target) {
    while (__hip_atomic_load(flag, __ATOMIC_RELAXED, __HIP_MEMORY_SCOPE_AGENT) < target)
        __builtin_amdgcn_s_sleep(2);
}

// ==== K12: blocks [0,800) LDS-histogram dst>>8 -> M[bin][blk];
//           blocks [800,864) transpose W -> Wt bf16;
//           blocks [864,1060) gate on histDone, then exclusive-scan M rows +
//           last-block coarse scan -> coarseBase, sentinels.
__global__ __launch_bounds__(256) void k_build1(
    const int* __restrict__ dst, int* __restrict__ M,
    const float* __restrict__ W, unsigned short* __restrict__ Wt,
    int* __restrict__ coarse, int* __restrict__ coarseBase,
    int* __restrict__ rowL, int* __restrict__ ssorted, int* __restrict__ flags) {
    int b = blockIdx.x, t = threadIdx.x;
    int lane = t & 63, w = t >> 6;

    if (b < NBLK) {                               // ---- histogram phase
        __shared__ int h[NBUCKET];
        if (t < NBUCKET) h[t] = 0;
        __syncthreads();
        int base = b * CHUNK;
        for (int i = base + t; i < base + CHUNK; i += 256)
            atomicAdd(&h[dst[i] >> 8], 1);
        __syncthreads();
        if (t < NBUCKET) M[(size_t)t * NBLK + b] = h[t];
        __threadfence();
        __syncthreads();
        if (t == 0) atomicAdd(&flags[0], 1);
        return;
    }
    if (b < NBLK + WT_BLOCKS) {                   // ---- W transpose
        int idx = (b - NBLK) * 256 + t;           // 0..16383
        int c = idx >> 6, k = idx & 63;
        Wt[idx] = f2bf(W[(size_t)k * HC + c]);
        return;
    }
    // ---- scan phase (gated)
    __shared__ int wsum[4];
    __shared__ int carry_s, tot_s, lastflag;
    int sb = b - NBLK - WT_BLOCKS;                // 0..195
    if (t == 0) { spin_until(&flags[0], NBLK); carry_s = 0; }
    __syncthreads();
    __threadfence();
    int* Mrow = M + (size_t)sb * NBLK;
    for (int c0 = 0; c0 < NBLK; c0 += 256) {
        int idx = c0 + t;
        int v = (idx < NBLK) ? Mrow[idx] : 0;
        int xs = v;
        #pragma unroll
        for (int off = 1; off < 64; off <<= 1) {
            int y = __shfl_up(xs, off);
            if (lane >= off) xs += y;
        }
        if (lane == 63) wsum[w] = xs;
        __syncthreads();
        if (t == 0) {
            int s0 = wsum[0], s1 = wsum[1], s2 = wsum[2], s3 = wsum[3];
            wsum[0] = 0; wsum[1] = s0; wsum[2] = s0 + s1; wsum[3] = s0 + s1 + s2;
            tot_s = s0 + s1 + s2 + s3;
        }
        __syncthreads();
        int excl = xs - v + wsum[w] + carry_s;
        if (idx < NBLK) Mrow[idx] = excl;
        __syncthreads();
        if (t == 0) carry_s += tot_s;
        __syncthreads();
    }
    if (t == 0) coarse[sb] = carry_s;
    __threadfence();
    if (t == 0) lastflag = (atomicAdd(&flags[1], 1) == NBUCKET - 1);
    __syncthreads();
    if (!lastflag) return;
    __threadfence();
    int v = (t < NBUCKET) ? coarse[t] : 0;
    int xs = v;
    #pragma unroll
    for (int off = 1; off < 64; off <<= 1) {
        int y = __shfl_up(xs, off);
        if (lane >= off) xs += y;
    }
    if (lane == 63) wsum[w] = xs;
    __syncthreads();
    if (t == 0) {
        int s0 = wsum[0], s1 = wsum[1], s2 = wsum[2];
        wsum[0] = 0; wsum[1] = s0; wsum[2] = s0 + s1; wsum[3] = s0 + s1 + s2;
    }
    __syncthreads();
    int excl = xs - v + wsum[w];
    if (t < NBUCKET) coarseBase[t] = excl;
    if (t == NBUCKET - 1) coarseBase[NBUCKET] = excl + v;   // = N_EDGES
    if (t == 0) rowL[N_NODES] = N_EDGES;
    if (t < 16) ssorted[N_EDGES + t] = 0;   // sentinel pad for k_node prefetch
}

// ==== K34: blocks [0,800) scatter packed (dloc<<16|src) into bucket-grouped tmp;
//           blocks [800,1056) strip-mined MFMA GEMM -> int8 rows + per-row scale;
//           blocks [1056,1252) gate on scatDone, then per-bucket CSR finalize.
__global__ __launch_bounds__(256) void k_build2(
    const int* __restrict__ src, const int* __restrict__ dst,
    const int* __restrict__ M, const int* __restrict__ coarseBase,
    int* __restrict__ tmp,
    const float* __restrict__ xf, const unsigned short* __restrict__ Wt,
    unsigned char* __restrict__ xq, float* __restrict__ scl,
    int* __restrict__ rowL, int* __restrict__ ssorted, int* __restrict__ flags) {
    __shared__ int shmem[520];   // scatter: cur[196] | gemm: rmax[16] | csr: h,cur,wsum
    int b = blockIdx.x, t = threadIdx.x;
    int lane = t & 63, w = t >> 6;

    if (b < NBLK) {                               // ---- scatter phase
        int* cur = shmem;
        if (t < NBUCKET) cur[t] = coarseBase[t] + M[(size_t)t * NBLK + b];
        __syncthreads();
        int base = b * CHUNK;
        for (int i = base + t; i < base + CHUNK; i += 256) {
            int d = dst[i];
            int pos = atomicAdd(&cur[d >> 8], 1);
            tmp[pos] = ((d & 255) << 16) | src[i];    // src < 65536 fits 16b
        }
        __threadfence();
        __syncthreads();
        if (t == 0) atomicAdd(&flags[2], 1);
        return;
    }
    if (b < NBLK + GEMM_WORKERS) {                // ---- GEMM phase (strip-mined)
        int* rmax = shmem;
        int g = b - NBLK;                         // 0..255
        int wv = t >> 6, l = t & 63;
        int r = l & 15, kg = l >> 4, ko = kg * 8;
        int drow = kg * 4;
        for (int rg = g; rg < GEMM_BLOCKS; rg += GEMM_WORKERS) {
            int row0 = rg * 16;
            const float* xrow = xf + (size_t)(row0 + r) * OUT_C;
            f32x4 a0 = *(const f32x4*)(xrow + ko);
            f32x4 a1 = *(const f32x4*)(xrow + ko + 4);
            f32x4 a2 = *(const f32x4*)(xrow + 32 + ko);
            f32x4 a3 = *(const f32x4*)(xrow + 32 + ko + 4);
            bf16x8 A0, A1;
            #pragma unroll
            for (int j = 0; j < 4; ++j) {
                A0[j]     = (short)f2bf(a0[j]);
                A0[j + 4] = (short)f2bf(a1[j]);
                A1[j]     = (short)f2bf(a2[j]);
                A1[j + 4] = (short)f2bf(a3[j]);
            }
            if (t < 16) rmax[t] = __float_as_int(1e-6f);
            __syncthreads();
            f32x4 acc0 = {0,0,0,0}, acc1 = {0,0,0,0}, acc2 = {0,0,0,0}, acc3 = {0,0,0,0};
#define DO_TILE(ACC, I) {                                                     \
            const unsigned short* wp = Wt + (size_t)(wv * 16 + (I) * 64 + r) * OUT_C + ko; \
            bf16x8 B0 = *(const bf16x8*)(wp);                                 \
            bf16x8 B1 = *(const bf16x8*)(wp + 32);                            \
            ACC = __builtin_amdgcn_mfma_f32_16x16x32_bf16(A0, B0, ACC, 0, 0, 0); \
            ACC = __builtin_amdgcn_mfma_f32_16x16x32_bf16(A1, B1, ACC, 0, 0, 0); }
            DO_TILE(acc0, 0) DO_TILE(acc1, 1) DO_TILE(acc2, 2) DO_TILE(acc3, 3)
#undef DO_TILE
            #pragma unroll
            for (int j = 0; j < 4; ++j) {
                float m = fmaxf(fmaxf(fabsf(acc0[j]), fabsf(acc1[j])),
                                fmaxf(fabsf(acc2[j]), fabsf(acc3[j])));
                atomicMax(&rmax[drow + j], __float_as_int(m));
            }
            __syncthreads();
            float is[4];
            #pragma unroll
            for (int j = 0; j < 4; ++j)
                is[j] = 127.0f / __int_as_float(rmax[drow + j]);
            #pragma unroll
            for (int j = 0; j < 4; ++j) {
                size_t base = (size_t)(row0 + drow + j) * HC + r;
                xq[base + wv * 16 + 0 * 64] = (unsigned char)((int)rintf(acc0[j] * is[j]) + 128);
                xq[base + wv * 16 + 1 * 64] = (unsigned char)((int)rintf(acc1[j] * is[j]) + 128);
                xq[base + wv * 16 + 2 * 64] = (unsigned char)((int)rintf(acc2[j] * is[j]) + 128);
                xq[base + wv * 16 + 3 * 64] = (unsigned char)((int)rintf(acc3[j] * is[j]) + 128);
            }
            if (t < 16) scl[row0 + t] = __int_as_float(rmax[t]) * (1.0f / 127.0f);
            __syncthreads();
        }
        return;
    }
    // ---- CSR finalize phase (gated on scatter only; overlaps gemm tail)
    int* h    = shmem;
    int* cur  = shmem + 256;
    int* wsum = shmem + 512;
    int cb = b - NBLK - GEMM_WORKERS;             // 0..195
    if (t == 0) spin_until(&flags[2], NBLK);
    __syncthreads();
    __threadfence();
    int s = coarseBase[cb], e = coarseBase[cb + 1];
    h[t] = 0;
    __syncthreads();
    for (int i = s + t; i < e; i += 256)
        atomicAdd(&h[(tmp[i] >> 16) & 255], 1);
    __syncthreads();
    int v = h[t];
    int xs = v;
    #pragma unroll
    for (int off = 1; off < 64; off <<= 1) {
        int y = __shfl_up(xs, off);
        if (lane >= off) xs += y;
    }
    if (lane == 63) wsum[w] = xs;
    __syncthreads();
    if (t == 0) {
        int s0 = wsum[0], s1 = wsum[1], s2 = wsum[2];
        wsum[0] = 0; wsum[1] = s0; wsum[2] = s0 + s1; wsum[3] = s0 + s1 + s2;
    }
    __syncthreads();
    int excl = xs - v + wsum[w];
    int n = cb * 256 + t;
    if (n < N_NODES) rowL[n] = s + excl;
    cur[t] = s + excl;
    __syncthreads();
    for (int i = s + t; i < e; i += 256) {
        int p = tmp[i];
        int pos = atomicAdd(&cur[(p >> 16) & 255], 1);
        ssorted[pos] = p & 0xFFFF;
    }
}

// ---------------- fused softmax + aggregate: one WAVE per node (r15-proven) ----
// int8 rows (256 B + scale). f = dequant(q) + xn via fma(cvt(q), s, xn-128s);
// acc trick: sum(ex*vc) = sum(ex*f) - xn*sum(ex)  -> vc never materialized.
__global__ __launch_bounds__(256) void k_node(
    const unsigned char* __restrict__ xq, const float* __restrict__ scl,
    const int* __restrict__ rowL, const int* __restrict__ ssorted,
    const float* __restrict__ att, const float* __restrict__ bias,
    float* __restrict__ out) {
    int w = threadIdx.x >> 6;
    int lane = threadIdx.x & 63;
    int n = blockIdx.x * 4 + w;                    // grid = 12500 exact
    int start = __builtin_amdgcn_readfirstlane(rowL[n]);
    int end   = __builtin_amdgcn_readfirstlane(rowL[n + 1]);
    int ne = end - start;
    const int* sp = ssorted + start;
    int c4 = lane << 2;
    const unsigned char* xp = xq + c4;
    // dequant dst row
    float sn = scl[n];
    float offn = 128.0f * sn;
    unsigned qn = *(const unsigned*)(xp + (size_t)n * HC);
    float4 xn;
    xn.x = ub0(qn) * sn - offn;
    xn.y = ub1(qn) * sn - offn;
    xn.z = ub2(qn) * sn - offn;
    xn.w = ub3(qn) * sn - offn;
    float4 at = *(const float4*)(att + c4);
    float4 at6 = make_float4(at.x * (0.6f * LOG2E), at.y * (0.6f * LOG2E),
                             at.z * (0.6f * LOG2E), at.w * (0.6f * LOG2E));
    float4 at4 = make_float4(at.x * (0.4f * LOG2E), at.y * (0.4f * LOG2E),
                             at.z * (0.4f * LOG2E), at.w * (0.4f * LOG2E));
    float4 accf = make_float4(0.f, 0.f, 0.f, 0.f);
    float den = 0.0f;

#define EDGE(qv, sv) {                                                    \
        float xo_x = xn.x - 128.0f * sv, xo_y = xn.y - 128.0f * sv;       \
        float xo_z = xn.z - 128.0f * sv, xo_w = xn.w - 128.0f * sv;       \
        float f0 = ub0(qv) * sv + xo_x;                                   \
        float f1 = ub1(qv) * sv + xo_y;                                   \
        float f2 = ub2(qv) * sv + xo_z;                                   \
        float f3 = ub3(qv) * sv + xo_w;                                   \
        float p;                                                          \
        p  = f0 * at6.x + fabsf(f0) * at4.x;                              \
        p += f1 * at6.y + fabsf(f1) * at4.y;                              \
        p += f2 * at6.z + fabsf(f2) * at4.z;                              \
        p += f3 * at6.w + fabsf(f3) * at4.w;                              \
        p = rowsum16(p);                                                  \
        float ex = exp2f(p);                                              \
        den += ex;                                                        \
        accf.x += ex * f0; accf.y += ex * f1;                             \
        accf.z += ex * f2; accf.w += ex * f3; }

    if (ne > 0) {
        // depth-2 pipeline; prefetches run into the 16-int sentinel pad
        int sa = sp[0];
        int sb = sp[1];
        unsigned qa = *(const unsigned*)(xp + (size_t)sa * HC);
        unsigned qb = *(const unsigned*)(xp + (size_t)sb * HC);
        float ssa = scl[sa], ssb = scl[sb];
        sa = sp[2];
        sb = sp[3];
        int i = 0;
        for (; i + 1 < ne; i += 2) {
            unsigned q0 = qa, q1 = qb;
            float s0 = ssa, s1 = ssb;
            qa = *(const unsigned*)(xp + (size_t)sa * HC);
            qb = *(const unsigned*)(xp + (size_t)sb * HC);
            ssa = scl[sa]; ssb = scl[sb];
            sa = sp[i + 4];
            sb = sp[i + 5];
            EDGE(q0, s0);
            EDGE(q1, s1);
        }
        if (i < ne) EDGE(qa, ssa);
    }
#undef EDGE

    float r = 1.0f / (den > 0.0f ? den : 1.0f);
    // acc = accf - xn*den  (exact; also handles den==0 -> acc=0 -> out=relu(bias))
    float4 b4 = *(const float4*)(bias + c4);
    float4 o;
    o.x = fmaxf((accf.x - xn.x * den) * r + b4.x, 0.0f);
    o.y = fmaxf((accf.y - xn.y * den) * r + b4.y, 0.0f);
    o.z = fmaxf((accf.z - xn.z * den) * r + b4.z, 0.0f);
    o.w = fmaxf((accf.w - xn.w * den) * r + b4.w, 0.0f);
    *(float4*)(out + (size_t)n * HC + c4) = o;
}

extern "C" void kernel_launch(void* const* d_in, const int* in_sizes, int n_in,
                              void* d_out, int out_size, void* d_ws, size_t ws_size,
                              hipStream_t stream) {
    const float* x    = (const float*)d_in[0];
    const int*   edge = (const int*)d_in[1];     // [2, E] int32
    const float* W    = (const float*)d_in[2];
    const float* att  = (const float*)d_in[3];
    const float* bias = (const float*)d_in[4];
    float* out = (float*)d_out;

    const int* src = edge;
    const int* dst = edge + N_EDGES;

    // workspace layout (8/16B-aligned)
    char* ws = (char*)d_ws;
    unsigned char* xq  = (unsigned char*)ws;              // 12,800,000 B (int8 xl)
    float* scl      = (float*)(ws + 12800000);            //   200,000 B (row scales)
    unsigned short* Wt = (unsigned short*)(ws + 13000000); //    32,768 B
    int* M          = (int*)(ws + 13032768);              //   627,200 B (196*800)
    int* coarse     = (int*)(ws + 13659968);              //       832 B
    int* coarseBase = (int*)(ws + 13660800);              //       832 B (197)
    int* flags      = (int*)(ws + 13661632);              //        64 B
    int* rowL       = (int*)(ws + 13661696);              //   200,064 B (50001)
    int* tmp        = (int*)(ws + 13861760);              // 3,200,000 B (packed)
    int* ssorted    = (int*)(ws + 17061760);              // 3,200,064 B (+16 pad)
    // total ~20.3 MB

    (void)hipMemsetAsync(flags, 0, 64, stream);
    k_build1<<<NBLK + WT_BLOCKS + NBUCKET, 256, 0, stream>>>(
        dst, M, W, Wt, coarse, coarseBase, rowL, ssorted, flags);
    k_build2<<<NBLK + GEMM_WORKERS + NBUCKET, 256, 0, stream>>>(
        src, dst, M, coarseBase, tmp, x, Wt, xq, scl, rowL, ssorted, flags);
    k_node<<<N_NODES / 4, 256, 0, stream>>>(xq, scl, rowL, ssorted, att, bias, out);
}

// Round 20
// 131.239 us; speedup vs baseline: 3.0432x; 3.0432x over previous
//
#include <hip/hip_runtime.h>
#include <math.h>

#define N_NODES 50000
#define N_EDGES 800000
#define HEADS 4
#define OUT_C 64
#define HC 256            // HEADS*OUT_C
#define NEG_SLOPE 0.2f
#define NBUCKET 196       // ceil(N_NODES/256)
#define CHUNK 1000
#define NBLK 800          // NBLK*CHUNK == N_EDGES exactly
#define WT_BLOCKS 64
#define GEMM_BLOCKS (N_NODES / 16)   // 3125
#define LOG2E 1.44269504f

typedef __attribute__((ext_vector_type(8))) short bf16x8;
typedef __attribute__((ext_vector_type(4))) float f32x4;

// float -> bf16 (round-to-nearest-even); inputs are finite
__device__ inline unsigned short f2bf(float f) {
    unsigned u = __float_as_uint(f);
    return (unsigned short)((u + 0x7FFFu + ((u >> 16) & 1u)) >> 16);
}

// byte k of u32 -> float; LLVM pattern-matches to v_cvt_f32_ubyte{0..3}
__device__ inline float ub0(unsigned q) { return (float)(q & 0xFFu); }
__device__ inline float ub1(unsigned q) { return (float)((q >> 8) & 0xFFu); }
__device__ inline float ub2(unsigned q) { return (float)((q >> 16) & 0xFFu); }
__device__ inline float ub3(unsigned q) { return (float)(q >> 24); }

// sum across the 16 lanes of a DPP row (head group) via row_ror adds: pure VALU
__device__ inline float rowsum16(float p) {
    int y;
    y = __builtin_amdgcn_update_dpp(0, __float_as_int(p), 0x121, 0xF, 0xF, false);
    p += __int_as_float(y);
    y = __builtin_amdgcn_update_dpp(0, __float_as_int(p), 0x122, 0xF, 0xF, false);
    p += __int_as_float(y);
    y = __builtin_amdgcn_update_dpp(0, __float_as_int(p), 0x124, 0xF, 0xF, false);
    p += __int_as_float(y);
    y = __builtin_amdgcn_update_dpp(0, __float_as_int(p), 0x128, 0xF, 0xF, false);
    p += __int_as_float(y);
    return p;
}

// ---- K1: blocks [0,NBLK) LDS-histogram dst>>8 -> M[bin][blk];
//          blocks [NBLK,NBLK+64) transpose W -> Wt bf16 (one also zeroes done)
__global__ void k_hist1(const int* __restrict__ dst, int* __restrict__ M,
                        const float* __restrict__ W, unsigned short* __restrict__ Wt,
                        int* __restrict__ done) {
    int b = blockIdx.x, t = threadIdx.x;
    if (b >= NBLK) {
        if (b == NBLK && t == 0) *done = 0;
        int idx = (b - NBLK) * 256 + t;     // 0..16383
        int c = idx >> 6, k = idx & 63;
        Wt[idx] = f2bf(W[(size_t)k * HC + c]);
        return;
    }
    __shared__ int h[NBUCKET];
    if (t < NBUCKET) h[t] = 0;
    __syncthreads();
    int base = b * CHUNK;
    for (int i = base + t; i < base + CHUNK; i += 256)
        atomicAdd(&h[dst[i] >> 8], 1);
    __syncthreads();
    if (t < NBUCKET) M[(size_t)t * NBLK + b] = h[t];
}

// ---- K2: 196 blocks; block b exclusive-scans M[b][0..799] in place;
//          last block scans bucket totals -> coarseBase, writes sentinels
__global__ void k_scan2(int* __restrict__ M, int* __restrict__ coarse,
                        int* __restrict__ coarseBase, int* __restrict__ rowL,
                        int* __restrict__ ssorted, int* __restrict__ done) {
    __shared__ int wsum[4];
    __shared__ int carry_s, tot_s, lastflag;
    int b = blockIdx.x, t = threadIdx.x;
    int lane = t & 63, w = t >> 6;
    if (t == 0) carry_s = 0;
    __syncthreads();
    int* Mrow = M + (size_t)b * NBLK;
    for (int c0 = 0; c0 < NBLK; c0 += 256) {
        int idx = c0 + t;
        int v = (idx < NBLK) ? Mrow[idx] : 0;
        int x = v;
        #pragma unroll
        for (int off = 1; off < 64; off <<= 1) {
            int y = __shfl_up(x, off);
            if (lane >= off) x += y;
        }
        if (lane == 63) wsum[w] = x;
        __syncthreads();
        if (t == 0) {
            int s0 = wsum[0], s1 = wsum[1], s2 = wsum[2], s3 = wsum[3];
            wsum[0] = 0; wsum[1] = s0; wsum[2] = s0 + s1; wsum[3] = s0 + s1 + s2;
            tot_s = s0 + s1 + s2 + s3;
        }
        __syncthreads();
        int excl = x - v + wsum[w] + carry_s;
        if (idx < NBLK) Mrow[idx] = excl;
        __syncthreads();
        if (t == 0) carry_s += tot_s;
        __syncthreads();
    }
    if (t == 0) coarse[b] = carry_s;
    __threadfence();
    if (t == 0) lastflag = (atomicAdd(done, 1) == NBUCKET - 1);
    __syncthreads();
    if (!lastflag) return;
    if (t == 0) *done = 0;                  // reset for next replay
    __threadfence();
    int v = (t < NBUCKET) ? coarse[t] : 0;
    int x = v;
    #pragma unroll
    for (int off = 1; off < 64; off <<= 1) {
        int y = __shfl_up(x, off);
        if (lane >= off) x += y;
    }
    if (lane == 63) wsum[w] = x;
    __syncthreads();
    if (t == 0) {
        int s0 = wsum[0], s1 = wsum[1], s2 = wsum[2];
        wsum[0] = 0; wsum[1] = s0; wsum[2] = s0 + s1; wsum[3] = s0 + s1 + s2;
    }
    __syncthreads();
    int excl = x - v + wsum[w];
    if (t < NBUCKET) coarseBase[t] = excl;
    if (t == NBUCKET - 1) coarseBase[NBUCKET] = excl + v;   // = N_EDGES
    if (t == 0) rowL[N_NODES] = N_EDGES;
    if (t < 16) ssorted[N_EDGES + t] = 0;   // sentinel pad for k_node prefetch
}

// ---- K3: blocks [0,NBLK) scatter packed (dloc<<16|src) into bucket-grouped tmp
//          via LDS cursors; blocks [NBLK,..) MFMA GEMM -> int8 rows + per-row scale
__global__ __launch_bounds__(256) void k_scatter_gemm(
    const int* __restrict__ src, const int* __restrict__ dst,
    const int* __restrict__ M, const int* __restrict__ coarseBase,
    int* __restrict__ tmp,
    const float* __restrict__ x, const unsigned short* __restrict__ Wt,
    unsigned char* __restrict__ xq, float* __restrict__ scl) {
    __shared__ int shmem[NBUCKET];          // scatter: cursors | gemm: rmax[16]
    int b = blockIdx.x, t = threadIdx.x;
    if (b < NBLK) {
        int* cur = shmem;
        if (t < NBUCKET) cur[t] = coarseBase[t] + M[(size_t)t * NBLK + b];
        __syncthreads();
        int base = b * CHUNK;
        for (int i = base + t; i < base + CHUNK; i += 256) {
            int d = dst[i];
            int pos = atomicAdd(&cur[d >> 8], 1);
            tmp[pos] = ((d & 255) << 16) | src[i];    // src < 65536 fits 16b
        }
        return;
    }
    // ---- MFMA GEMM: A: row=l&15, k=(l>>4)*8+j; D: col=l&15, row=(l>>4)*4+j
    int* rmax = shmem;                       // 16 ints: per-row |max| (f32 bits)
    int wv = t >> 6, l = t & 63;
    int row0 = (b - NBLK) * 16;
    int r = l & 15, kg = l >> 4, ko = kg * 8;
    const float* xrow = x + (size_t)(row0 + r) * OUT_C;
    f32x4 a0 = *(const f32x4*)(xrow + ko);
    f32x4 a1 = *(const f32x4*)(xrow + ko + 4);
    f32x4 a2 = *(const f32x4*)(xrow + 32 + ko);
    f32x4 a3 = *(const f32x4*)(xrow + 32 + ko + 4);
    bf16x8 A0, A1;
    #pragma unroll
    for (int j = 0; j < 4; ++j) {
        A0[j]     = (short)f2bf(a0[j]);
        A0[j + 4] = (short)f2bf(a1[j]);
        A1[j]     = (short)f2bf(a2[j]);
        A1[j + 4] = (short)f2bf(a3[j]);
    }
    if (t < 16) rmax[t] = __float_as_int(1e-6f);   // positive floats: int-monotonic
    __syncthreads();
    f32x4 acc0 = {0,0,0,0}, acc1 = {0,0,0,0}, acc2 = {0,0,0,0}, acc3 = {0,0,0,0};
#define DO_TILE(ACC, I) {                                                     \
        const unsigned short* wp = Wt + (size_t)(wv * 16 + (I) * 64 + r) * OUT_C + ko; \
        bf16x8 B0 = *(const bf16x8*)(wp);                                     \
        bf16x8 B1 = *(const bf16x8*)(wp + 32);                                \
        ACC = __builtin_amdgcn_mfma_f32_16x16x32_bf16(A0, B0, ACC, 0, 0, 0);  \
        ACC = __builtin_amdgcn_mfma_f32_16x16x32_bf16(A1, B1, ACC, 0, 0, 0); }
    DO_TILE(acc0, 0) DO_TILE(acc1, 1) DO_TILE(acc2, 2) DO_TILE(acc3, 3)
#undef DO_TILE
    int drow = kg * 4;
    #pragma unroll
    for (int j = 0; j < 4; ++j) {
        float m = fmaxf(fmaxf(fabsf(acc0[j]), fabsf(acc1[j])),
                        fmaxf(fabsf(acc2[j]), fabsf(acc3[j])));
        atomicMax(&rmax[drow + j], __float_as_int(m));
    }
    __syncthreads();
    float is[4];
    #pragma unroll
    for (int j = 0; j < 4; ++j)
        is[j] = 127.0f / __int_as_float(rmax[drow + j]);
    #pragma unroll
    for (int j = 0; j < 4; ++j) {
        size_t base = (size_t)(row0 + drow + j) * HC + r;
        xq[base + wv * 16 + 0 * 64] = (unsigned char)((int)rintf(acc0[j] * is[j]) + 128);
        xq[base + wv * 16 + 1 * 64] = (unsigned char)((int)rintf(acc1[j] * is[j]) + 128);
        xq[base + wv * 16 + 2 * 64] = (unsigned char)((int)rintf(acc2[j] * is[j]) + 128);
        xq[base + wv * 16 + 3 * 64] = (unsigned char)((int)rintf(acc3[j] * is[j]) + 128);
    }
    if (t < 16) scl[row0 + t] = __int_as_float(rmax[t]) * (1.0f / 127.0f);
}

// ---- K4: one block per bucket: LDS hist over local 256 nodes + LDS scan ->
//          rowL (global CSR starts) and LDS cursors -> ssorted. LDS atomics only.
__global__ void k_csr(const int* __restrict__ tmp, const int* __restrict__ coarseBase,
                      int* __restrict__ rowL, int* __restrict__ ssorted) {
    __shared__ int h[256];
    __shared__ int cur[256];
    __shared__ int wsum[4];
    int b = blockIdx.x, t = threadIdx.x;
    int lane = t & 63, w = t >> 6;
    int s = coarseBase[b], e = coarseBase[b + 1];
    h[t] = 0;
    __syncthreads();
    for (int i = s + t; i < e; i += 256)
        atomicAdd(&h[(tmp[i] >> 16) & 255], 1);
    __syncthreads();
    int v = h[t];
    int x = v;
    #pragma unroll
    for (int off = 1; off < 64; off <<= 1) {
        int y = __shfl_up(x, off);
        if (lane >= off) x += y;
    }
    if (lane == 63) wsum[w] = x;
    __syncthreads();
    if (t == 0) {
        int s0 = wsum[0], s1 = wsum[1], s2 = wsum[2];
        wsum[0] = 0; wsum[1] = s0; wsum[2] = s0 + s1; wsum[3] = s0 + s1 + s2;
    }
    __syncthreads();
    int excl = x - v + wsum[w];
    int n = b * 256 + t;
    if (n < N_NODES) rowL[n] = s + excl;
    cur[t] = s + excl;
    __syncthreads();
    for (int i = s + t; i < e; i += 256) {
        int p = tmp[i];
        int pos = atomicAdd(&cur[(p >> 16) & 255], 1);
        ssorted[pos] = p & 0xFFFF;
    }
}

// ---------------- fused softmax + aggregate: one WAVE per node ----------------
// int8 rows (256 B + scale). f = dequant(q) + xn computed as fma(cvt(q), s, xn-128s);
// acc trick: sum(ex*vc) = sum(ex*f) - xn*sum(ex)  -> vc never materialized.
__global__ __launch_bounds__(256) void k_node(
    const unsigned char* __restrict__ xq, const float* __restrict__ scl,
    const int* __restrict__ rowL, const int* __restrict__ ssorted,
    const float* __restrict__ att, const float* __restrict__ bias,
    float* __restrict__ out) {
    int w = threadIdx.x >> 6;
    int lane = threadIdx.x & 63;
    int n = blockIdx.x * 4 + w;                    // grid = 12500 exact
    int start = __builtin_amdgcn_readfirstlane(rowL[n]);
    int end   = __builtin_amdgcn_readfirstlane(rowL[n + 1]);
    int ne = end - start;
    const int* sp = ssorted + start;
    int c4 = lane << 2;
    const unsigned char* xp = xq + c4;
    // dequant dst row
    float sn = scl[n];
    float offn = 128.0f * sn;
    unsigned qn = *(const unsigned*)(xp + (size_t)n * HC);
    float4 xn;
    xn.x = ub0(qn) * sn - offn;
    xn.y = ub1(qn) * sn - offn;
    xn.z = ub2(qn) * sn - offn;
    xn.w = ub3(qn) * sn - offn;
    float4 at = *(const float4*)(att + c4);
    float4 at6 = make_float4(at.x * (0.6f * LOG2E), at.y * (0.6f * LOG2E),
                             at.z * (0.6f * LOG2E), at.w * (0.6f * LOG2E));
    float4 at4 = make_float4(at.x * (0.4f * LOG2E), at.y * (0.4f * LOG2E),
                             at.z * (0.4f * LOG2E), at.w * (0.4f * LOG2E));
    float4 accf = make_float4(0.f, 0.f, 0.f, 0.f);
    float den = 0.0f;

#define EDGE(qv, sv) {                                                    \
        float xo_x = xn.x - 128.0f * sv, xo_y = xn.y - 128.0f * sv;       \
        float xo_z = xn.z - 128.0f * sv, xo_w = xn.w - 128.0f * sv;       \
        float f0 = ub0(qv) * sv + xo_x;                                   \
        float f1 = ub1(qv) * sv + xo_y;                                   \
        float f2 = ub2(qv) * sv + xo_z;                                   \
        float f3 = ub3(qv) * sv + xo_w;                                   \
        float p;                                                          \
        p  = f0 * at6.x + fabsf(f0) * at4.x;                              \
        p += f1 * at6.y + fabsf(f1) * at4.y;                              \
        p += f2 * at6.z + fabsf(f2) * at4.z;                              \
        p += f3 * at6.w + fabsf(f3) * at4.w;                              \
        p = rowsum16(p);                                                  \
        float ex = exp2f(p);                                              \
        den += ex;                                                        \
        accf.x += ex * f0; accf.y += ex * f1;                             \
        accf.z += ex * f2; accf.w += ex * f3; }

    if (ne > 0) {
        // depth-2 pipeline; prefetches run into the 16-int sentinel pad
        int sa = sp[0];
        int sb = sp[1];
        unsigned qa = *(const unsigned*)(xp + (size_t)sa * HC);
        unsigned qb = *(const unsigned*)(xp + (size_t)sb * HC);
        float ssa = scl[sa], ssb = scl[sb];
        sa = sp[2];
        sb = sp[3];
        int i = 0;
        for (; i + 1 < ne; i += 2) {
            unsigned q0 = qa, q1 = qb;
            float s0 = ssa, s1 = ssb;
            qa = *(const unsigned*)(xp + (size_t)sa * HC);
            qb = *(const unsigned*)(xp + (size_t)sb * HC);
            ssa = scl[sa]; ssb = scl[sb];
            sa = sp[i + 4];
            sb = sp[i + 5];
            EDGE(q0, s0);
            EDGE(q1, s1);
        }
        if (i < ne) EDGE(qa, ssa);
    }
#undef EDGE

    float r = 1.0f / (den > 0.0f ? den : 1.0f);
    // acc = accf - xn*den  (exact; also handles den==0 -> acc=0 -> out=relu(bias))
    float4 b4 = *(const float4*)(bias + c4);
    float4 o;
    o.x = fmaxf((accf.x - xn.x * den) * r + b4.x, 0.0f);
    o.y = fmaxf((accf.y - xn.y * den) * r + b4.y, 0.0f);
    o.z = fmaxf((accf.z - xn.z * den) * r + b4.z, 0.0f);
    o.w = fmaxf((accf.w - xn.w * den) * r + b4.w, 0.0f);
    *(float4*)(out + (size_t)n * HC + c4) = o;
}

extern "C" void kernel_launch(void* const* d_in, const int* in_sizes, int n_in,
                              void* d_out, int out_size, void* d_ws, size_t ws_size,
                              hipStream_t stream) {
    const float* x    = (const float*)d_in[0];
    const int*   edge = (const int*)d_in[1];     // [2, E] int32
    const float* W    = (const float*)d_in[2];
    const float* att  = (const float*)d_in[3];
    const float* bias = (const float*)d_in[4];
    float* out = (float*)d_out;

    const int* src = edge;
    const int* dst = edge + N_EDGES;

    // workspace layout (8/16B-aligned)
    char* ws = (char*)d_ws;
    unsigned char* xq  = (unsigned char*)ws;              // 12,800,000 B (int8 xl)
    float* scl      = (float*)(ws + 12800000);            //   200,000 B (row scales)
    unsigned short* Wt = (unsigned short*)(ws + 13000000); //    32,768 B
    int* M          = (int*)(ws + 13032768);              //   627,200 B (196*800)
    int* coarse     = (int*)(ws + 13659968);              //       832 B
    int* coarseBase = (int*)(ws + 13660800);              //       832 B (197)
    int* done       = (int*)(ws + 13661632);              //        64 B
    int* rowL       = (int*)(ws + 13661696);              //   200,064 B (50001)
    int* tmp        = (int*)(ws + 13861760);              // 3,200,000 B (packed)
    int* ssorted    = (int*)(ws + 17061760);              // 3,200,064 B (+16 pad)
    // total ~20.3 MB

    k_hist1<<<NBLK + WT_BLOCKS, 256, 0, stream>>>(dst, M, W, Wt, done);
    k_scan2<<<NBUCKET, 256, 0, stream>>>(M, coarse, coarseBase, rowL, ssorted, done);
    k_scatter_gemm<<<NBLK + GEMM_BLOCKS, 256, 0, stream>>>(src, dst, M, coarseBase,
                                                           tmp, x, Wt, xq, scl);
    k_csr<<<NBUCKET, 256, 0, stream>>>(tmp, coarseBase, rowL, ssorted);
    k_node<<<N_NODES / 4, 256, 0, stream>>>(xq, scl, rowL, ssorted, att, bias, out);
}

// Round 21
// 128.667 us; speedup vs baseline: 3.1040x; 1.0200x over previous
//
#include <hip/hip_runtime.h>
#include <math.h>

#define N_NODES 50000
#define N_EDGES 800000
#define HEADS 4
#define OUT_C 64
#define HC 256            // HEADS*OUT_C
#define NEG_SLOPE 0.2f
#define NBUCKET 196       // ceil(N_NODES/256)
#define CHUNK 2000
#define NBLK 400          // NBLK*CHUNK == N_EDGES exactly
#define WT_BLOCKS 64
#define GEMM_BLOCKS (N_NODES / 16)   // 3125
#define LOG2E 1.44269504f

typedef __attribute__((ext_vector_type(8))) short bf16x8;
typedef __attribute__((ext_vector_type(4))) float f32x4;

// float -> bf16 (round-to-nearest-even); inputs are finite
__device__ inline unsigned short f2bf(float f) {
    unsigned u = __float_as_uint(f);
    return (unsigned short)((u + 0x7FFFu + ((u >> 16) & 1u)) >> 16);
}

// byte k of u32 -> float; LLVM pattern-matches to v_cvt_f32_ubyte{0..3}
__device__ inline float ub0(unsigned q) { return (float)(q & 0xFFu); }
__device__ inline float ub1(unsigned q) { return (float)((q >> 8) & 0xFFu); }
__device__ inline float ub2(unsigned q) { return (float)((q >> 16) & 0xFFu); }
__device__ inline float ub3(unsigned q) { return (float)(q >> 24); }

// sum across the 16 lanes of a DPP row (head group) via row_ror adds: pure VALU
__device__ inline float rowsum16(float p) {
    int y;
    y = __builtin_amdgcn_update_dpp(0, __float_as_int(p), 0x121, 0xF, 0xF, false);
    p += __int_as_float(y);
    y = __builtin_amdgcn_update_dpp(0, __float_as_int(p), 0x122, 0xF, 0xF, false);
    p += __int_as_float(y);
    y = __builtin_amdgcn_update_dpp(0, __float_as_int(p), 0x124, 0xF, 0xF, false);
    p += __int_as_float(y);
    y = __builtin_amdgcn_update_dpp(0, __float_as_int(p), 0x128, 0xF, 0xF, false);
    p += __int_as_float(y);
    return p;
}

// ---- K1: blocks [0,NBLK) LDS-histogram dst>>8 -> M[bin][blk] (int4 loads);
//          blocks [NBLK,NBLK+64) transpose W -> Wt bf16 (one also zeroes done)
__global__ void k_hist1(const int* __restrict__ dst, int* __restrict__ M,
                        const float* __restrict__ W, unsigned short* __restrict__ Wt,
                        int* __restrict__ done) {
    int b = blockIdx.x, t = threadIdx.x;
    if (b >= NBLK) {
        if (b == NBLK && t == 0) *done = 0;
        int idx = (b - NBLK) * 256 + t;     // 0..16383
        int c = idx >> 6, k = idx & 63;
        Wt[idx] = f2bf(W[(size_t)k * HC + c]);
        return;
    }
    __shared__ int h[NBUCKET];
    if (t < NBUCKET) h[t] = 0;
    __syncthreads();
    const int4* d4 = (const int4*)(dst + b * CHUNK);   // 16B-aligned (CHUNK*4 % 16 == 0)
    for (int j = t; j < CHUNK / 4; j += 256) {
        int4 d = d4[j];
        atomicAdd(&h[d.x >> 8], 1);
        atomicAdd(&h[d.y >> 8], 1);
        atomicAdd(&h[d.z >> 8], 1);
        atomicAdd(&h[d.w >> 8], 1);
    }
    __syncthreads();
    if (t < NBUCKET) M[(size_t)t * NBLK + b] = h[t];
}

// ---- K2: 196 blocks; block b exclusive-scans M[b][0..NBLK) in place;
//          last block scans bucket totals -> coarseBase, writes sentinels
__global__ void k_scan2(int* __restrict__ M, int* __restrict__ coarse,
                        int* __restrict__ coarseBase, int* __restrict__ rowL,
                        int* __restrict__ ssorted, int* __restrict__ done) {
    __shared__ int wsum[4];
    __shared__ int carry_s, tot_s, lastflag;
    int b = blockIdx.x, t = threadIdx.x;
    int lane = t & 63, w = t >> 6;
    if (t == 0) carry_s = 0;
    __syncthreads();
    int* Mrow = M + (size_t)b * NBLK;
    for (int c0 = 0; c0 < NBLK; c0 += 256) {
        int idx = c0 + t;
        int v = (idx < NBLK) ? Mrow[idx] : 0;
        int x = v;
        #pragma unroll
        for (int off = 1; off < 64; off <<= 1) {
            int y = __shfl_up(x, off);
            if (lane >= off) x += y;
        }
        if (lane == 63) wsum[w] = x;
        __syncthreads();
        if (t == 0) {
            int s0 = wsum[0], s1 = wsum[1], s2 = wsum[2], s3 = wsum[3];
            wsum[0] = 0; wsum[1] = s0; wsum[2] = s0 + s1; wsum[3] = s0 + s1 + s2;
            tot_s = s0 + s1 + s2 + s3;
        }
        __syncthreads();
        int excl = x - v + wsum[w] + carry_s;
        if (idx < NBLK) Mrow[idx] = excl;
        __syncthreads();
        if (t == 0) carry_s += tot_s;
        __syncthreads();
    }
    if (t == 0) coarse[b] = carry_s;
    __threadfence();
    if (t == 0) lastflag = (atomicAdd(done, 1) == NBUCKET - 1);
    __syncthreads();
    if (!lastflag) return;
    if (t == 0) *done = 0;                  // reset for next replay
    __threadfence();
    int v = (t < NBUCKET) ? coarse[t] : 0;
    int x = v;
    #pragma unroll
    for (int off = 1; off < 64; off <<= 1) {
        int y = __shfl_up(x, off);
        if (lane >= off) x += y;
    }
    if (lane == 63) wsum[w] = x;
    __syncthreads();
    if (t == 0) {
        int s0 = wsum[0], s1 = wsum[1], s2 = wsum[2];
        wsum[0] = 0; wsum[1] = s0; wsum[2] = s0 + s1; wsum[3] = s0 + s1 + s2;
    }
    __syncthreads();
    int excl = x - v + wsum[w];
    if (t < NBUCKET) coarseBase[t] = excl;
    if (t == NBUCKET - 1) coarseBase[NBUCKET] = excl + v;   // = N_EDGES
    if (t == 0) rowL[N_NODES] = N_EDGES;
    if (t < 16) ssorted[N_EDGES + t] = 0;   // sentinel pad for k_node prefetch
}

// ---- K3: blocks [0,NBLK) scatter packed (dloc<<16|src) into bucket-grouped tmp
//          via LDS cursors (int4 loads); blocks [NBLK,..) MFMA GEMM -> int8 + scale
__global__ __launch_bounds__(256) void k_scatter_gemm(
    const int* __restrict__ src, const int* __restrict__ dst,
    const int* __restrict__ M, const int* __restrict__ coarseBase,
    int* __restrict__ tmp,
    const float* __restrict__ x, const unsigned short* __restrict__ Wt,
    unsigned char* __restrict__ xq, float* __restrict__ scl) {
    __shared__ int shmem[NBUCKET];          // scatter: cursors | gemm: rmax[16]
    int b = blockIdx.x, t = threadIdx.x;
    if (b < NBLK) {
        int* cur = shmem;
        if (t < NBUCKET) cur[t] = coarseBase[t] + M[(size_t)t * NBLK + b];
        __syncthreads();
        const int4* d4 = (const int4*)(dst + b * CHUNK);
        const int4* s4 = (const int4*)(src + b * CHUNK);
        for (int j = t; j < CHUNK / 4; j += 256) {
            int4 d = d4[j];
            int4 s = s4[j];
            int p0 = atomicAdd(&cur[d.x >> 8], 1);
            tmp[p0] = ((d.x & 255) << 16) | s.x;
            int p1 = atomicAdd(&cur[d.y >> 8], 1);
            tmp[p1] = ((d.y & 255) << 16) | s.y;
            int p2 = atomicAdd(&cur[d.z >> 8], 1);
            tmp[p2] = ((d.z & 255) << 16) | s.z;
            int p3 = atomicAdd(&cur[d.w >> 8], 1);
            tmp[p3] = ((d.w & 255) << 16) | s.w;
        }
        return;
    }
    // ---- MFMA GEMM: A: row=l&15, k=(l>>4)*8+j; D: col=l&15, row=(l>>4)*4+j
    int* rmax = shmem;                       // 16 ints: per-row |max| (f32 bits)
    int wv = t >> 6, l = t & 63;
    int row0 = (b - NBLK) * 16;
    int r = l & 15, kg = l >> 4, ko = kg * 8;
    const float* xrow = x + (size_t)(row0 + r) * OUT_C;
    f32x4 a0 = *(const f32x4*)(xrow + ko);
    f32x4 a1 = *(const f32x4*)(xrow + ko + 4);
    f32x4 a2 = *(const f32x4*)(xrow + 32 + ko);
    f32x4 a3 = *(const f32x4*)(xrow + 32 + ko + 4);
    bf16x8 A0, A1;
    #pragma unroll
    for (int j = 0; j < 4; ++j) {
        A0[j]     = (short)f2bf(a0[j]);
        A0[j + 4] = (short)f2bf(a1[j]);
        A1[j]     = (short)f2bf(a2[j]);
        A1[j + 4] = (short)f2bf(a3[j]);
    }
    if (t < 16) rmax[t] = __float_as_int(1e-6f);   // positive floats: int-monotonic
    __syncthreads();
    f32x4 acc0 = {0,0,0,0}, acc1 = {0,0,0,0}, acc2 = {0,0,0,0}, acc3 = {0,0,0,0};
#define DO_TILE(ACC, I) {                                                     \
        const unsigned short* wp = Wt + (size_t)(wv * 16 + (I) * 64 + r) * OUT_C + ko; \
        bf16x8 B0 = *(const bf16x8*)(wp);                                     \
        bf16x8 B1 = *(const bf16x8*)(wp + 32);                                \
        ACC = __builtin_amdgcn_mfma_f32_16x16x32_bf16(A0, B0, ACC, 0, 0, 0);  \
        ACC = __builtin_amdgcn_mfma_f32_16x16x32_bf16(A1, B1, ACC, 0, 0, 0); }
    DO_TILE(acc0, 0) DO_TILE(acc1, 1) DO_TILE(acc2, 2) DO_TILE(acc3, 3)
#undef DO_TILE
    int drow = kg * 4;
    #pragma unroll
    for (int j = 0; j < 4; ++j) {
        float m = fmaxf(fmaxf(fabsf(acc0[j]), fabsf(acc1[j])),
                        fmaxf(fabsf(acc2[j]), fabsf(acc3[j])));
        atomicMax(&rmax[drow + j], __float_as_int(m));
    }
    __syncthreads();
    float is[4];
    #pragma unroll
    for (int j = 0; j < 4; ++j)
        is[j] = 127.0f / __int_as_float(rmax[drow + j]);
    #pragma unroll
    for (int j = 0; j < 4; ++j) {
        size_t base = (size_t)(row0 + drow + j) * HC + r;
        xq[base + wv * 16 + 0 * 64] = (unsigned char)((int)rintf(acc0[j] * is[j]) + 128);
        xq[base + wv * 16 + 1 * 64] = (unsigned char)((int)rintf(acc1[j] * is[j]) + 128);
        xq[base + wv * 16 + 2 * 64] = (unsigned char)((int)rintf(acc2[j] * is[j]) + 128);
        xq[base + wv * 16 + 3 * 64] = (unsigned char)((int)rintf(acc3[j] * is[j]) + 128);
    }
    if (t < 16) scl[row0 + t] = __int_as_float(rmax[t]) * (1.0f / 127.0f);
}

// ---- K4: one block per bucket: LDS hist over local 256 nodes + LDS scan ->
//          rowL (global CSR starts) and LDS cursors -> ssorted. LDS atomics only.
__global__ void k_csr(const int* __restrict__ tmp, const int* __restrict__ coarseBase,
                      int* __restrict__ rowL, int* __restrict__ ssorted) {
    __shared__ int h[256];
    __shared__ int cur[256];
    __shared__ int wsum[4];
    int b = blockIdx.x, t = threadIdx.x;
    int lane = t & 63, w = t >> 6;
    int s = coarseBase[b], e = coarseBase[b + 1];
    h[t] = 0;
    __syncthreads();
    for (int i = s + t; i < e; i += 256)
        atomicAdd(&h[(tmp[i] >> 16) & 255], 1);
    __syncthreads();
    int v = h[t];
    int x = v;
    #pragma unroll
    for (int off = 1; off < 64; off <<= 1) {
        int y = __shfl_up(x, off);
        if (lane >= off) x += y;
    }
    if (lane == 63) wsum[w] = x;
    __syncthreads();
    if (t == 0) {
        int s0 = wsum[0], s1 = wsum[1], s2 = wsum[2];
        wsum[0] = 0; wsum[1] = s0; wsum[2] = s0 + s1; wsum[3] = s0 + s1 + s2;
    }
    __syncthreads();
    int excl = x - v + wsum[w];
    int n = b * 256 + t;
    if (n < N_NODES) rowL[n] = s + excl;
    cur[t] = s + excl;
    __syncthreads();
    for (int i = s + t; i < e; i += 256) {
        int p = tmp[i];
        int pos = atomicAdd(&cur[(p >> 16) & 255], 1);
        ssorted[pos] = p & 0xFFFF;
    }
}

// ---------------- fused softmax + aggregate: one WAVE per node ----------------
// int8 rows (256 B + scale). f = dequant(q) + xn computed as fma(cvt(q), s, xn-128s);
// acc trick: sum(ex*vc) = sum(ex*f) - xn*sum(ex)  -> vc never materialized.
__global__ __launch_bounds__(256) void k_node(
    const unsigned char* __restrict__ xq, const float* __restrict__ scl,
    const int* __restrict__ rowL, const int* __restrict__ ssorted,
    const float* __restrict__ att, const float* __restrict__ bias,
    float* __restrict__ out) {
    int w = threadIdx.x >> 6;
    int lane = threadIdx.x & 63;
    int n = blockIdx.x * 4 + w;                    // grid = 12500 exact
    int start = __builtin_amdgcn_readfirstlane(rowL[n]);
    int end   = __builtin_amdgcn_readfirstlane(rowL[n + 1]);
    int ne = end - start;
    const int* sp = ssorted + start;
    int c4 = lane << 2;
    const unsigned char* xp = xq + c4;
    // dequant dst row
    float sn = scl[n];
    float offn = 128.0f * sn;
    unsigned qn = *(const unsigned*)(xp + (size_t)n * HC);
    float4 xn;
    xn.x = ub0(qn) * sn - offn;
    xn.y = ub1(qn) * sn - offn;
    xn.z = ub2(qn) * sn - offn;
    xn.w = ub3(qn) * sn - offn;
    float4 at = *(const float4*)(att + c4);
    float4 at6 = make_float4(at.x * (0.6f * LOG2E), at.y * (0.6f * LOG2E),
                             at.z * (0.6f * LOG2E), at.w * (0.6f * LOG2E));
    float4 at4 = make_float4(at.x * (0.4f * LOG2E), at.y * (0.4f * LOG2E),
                             at.z * (0.4f * LOG2E), at.w * (0.4f * LOG2E));
    float4 accf = make_float4(0.f, 0.f, 0.f, 0.f);
    float den = 0.0f;

#define EDGE(qv, sv) {                                                    \
        float xo_x = xn.x - 128.0f * sv, xo_y = xn.y - 128.0f * sv;       \
        float xo_z = xn.z - 128.0f * sv, xo_w = xn.w - 128.0f * sv;       \
        float f0 = ub0(qv) * sv + xo_x;                                   \
        float f1 = ub1(qv) * sv + xo_y;                                   \
        float f2 = ub2(qv) * sv + xo_z;                                   \
        float f3 = ub3(qv) * sv + xo_w;                                   \
        float p;                                                          \
        p  = f0 * at6.x + fabsf(f0) * at4.x;                              \
        p += f1 * at6.y + fabsf(f1) * at4.y;                              \
        p += f2 * at6.z + fabsf(f2) * at4.z;                              \
        p += f3 * at6.w + fabsf(f3) * at4.w;                              \
        p = rowsum16(p);                                                  \
        float ex = exp2f(p);                                              \
        den += ex;                                                        \
        accf.x += ex * f0; accf.y += ex * f1;                             \
        accf.z += ex * f2; accf.w += ex * f3; }

    if (ne > 0) {
        // depth-2 pipeline; prefetches run into the 16-int sentinel pad
        int sa = sp[0];
        int sb = sp[1];
        unsigned qa = *(const unsigned*)(xp + (size_t)sa * HC);
        unsigned qb = *(const unsigned*)(xp + (size_t)sb * HC);
        float ssa = scl[sa], ssb = scl[sb];
        sa = sp[2];
        sb = sp[3];
        int i = 0;
        for (; i + 1 < ne; i += 2) {
            unsigned q0 = qa, q1 = qb;
            float s0 = ssa, s1 = ssb;
            qa = *(const unsigned*)(xp + (size_t)sa * HC);
            qb = *(const unsigned*)(xp + (size_t)sb * HC);
            ssa = scl[sa]; ssb = scl[sb];
            sa = sp[i + 4];
            sb = sp[i + 5];
            EDGE(q0, s0);
            EDGE(q1, s1);
        }
        if (i < ne) EDGE(qa, ssa);
    }
#undef EDGE

    float r = 1.0f / (den > 0.0f ? den : 1.0f);
    // acc = accf - xn*den  (exact; also handles den==0 -> acc=0 -> out=relu(bias))
    float4 b4 = *(const float4*)(bias + c4);
    float4 o;
    o.x = fmaxf((accf.x - xn.x * den) * r + b4.x, 0.0f);
    o.y = fmaxf((accf.y - xn.y * den) * r + b4.y, 0.0f);
    o.z = fmaxf((accf.z - xn.z * den) * r + b4.z, 0.0f);
    o.w = fmaxf((accf.w - xn.w * den) * r + b4.w, 0.0f);
    *(float4*)(out + (size_t)n * HC + c4) = o;
}

extern "C" void kernel_launch(void* const* d_in, const int* in_sizes, int n_in,
                              void* d_out, int out_size, void* d_ws, size_t ws_size,
                              hipStream_t stream) {
    const float* x    = (const float*)d_in[0];
    const int*   edge = (const int*)d_in[1];     // [2, E] int32
    const float* W    = (const float*)d_in[2];
    const float* att  = (const float*)d_in[3];
    const float* bias = (const float*)d_in[4];
    float* out = (float*)d_out;

    const int* src = edge;
    const int* dst = edge + N_EDGES;

    // workspace layout (8/16B-aligned)
    char* ws = (char*)d_ws;
    unsigned char* xq  = (unsigned char*)ws;              // 12,800,000 B (int8 xl)
    float* scl      = (float*)(ws + 12800000);            //   200,000 B (row scales)
    unsigned short* Wt = (unsigned short*)(ws + 13000000); //    32,768 B
    int* M          = (int*)(ws + 13032768);              //   313,600 B (196*400)
    int* coarse     = (int*)(ws + 13659968);              //       832 B
    int* coarseBase = (int*)(ws + 13660800);              //       832 B (197)
    int* done       = (int*)(ws + 13661632);              //        64 B
    int* rowL       = (int*)(ws + 13661696);              //   200,064 B (50001)
    int* tmp        = (int*)(ws + 13861760);              // 3,200,000 B (packed)
    int* ssorted    = (int*)(ws + 17061760);              // 3,200,064 B (+16 pad)
    // total ~20.3 MB

    k_hist1<<<NBLK + WT_BLOCKS, 256, 0, stream>>>(dst, M, W, Wt, done);
    k_scan2<<<NBUCKET, 256, 0, stream>>>(M, coarse, coarseBase, rowL, ssorted, done);
    k_scatter_gemm<<<NBLK + GEMM_BLOCKS, 256, 0, stream>>>(src, dst, M, coarseBase,
                                                           tmp, x, Wt, xq, scl);
    k_csr<<<NBUCKET, 256, 0, stream>>>(tmp, coarseBase, rowL, ssorted);
    k_node<<<N_NODES / 4, 256, 0, stream>>>(xq, scl, rowL, ssorted, att, bias, out);
}